// Round 1
// baseline (2879.516 us; speedup 1.0000x reference)
//
#include <hip/hip_runtime.h>
#include <hip/hip_bf16.h>
#include <math.h>

// Problem constants (from reference)
#define INPUT_DIM 1024
#define STATE_DIM 16
#define CONV_KK   4
#define INNER     2048          // INPUT_DIM * EXPAND
#define BATCH     2
#define SEQ       2048
#define M_TOT     (BATCH*SEQ)   // 4096
#define N1        (2*INNER)     // 4096
#define K1        INPUT_DIM     // 1024
#define N2        INPUT_DIM     // 1024
#define K2        INNER         // 2048

__device__ __forceinline__ float softplusf(float x) {
    return x > 20.f ? x : log1pf(expf(x));
}
__device__ __forceinline__ float sigmoidf_(float x) {
    return 1.f / (1.f + expf(-x));
}

// ---------------------------------------------------------------------------
// Tiled f32 GEMM, NT form: C[m][n] = sum_k A[m*K+k] * B[n*K+k]
// BM=BN=128, BK=8, 256 threads, 8x8 micro-tile per thread.
// ---------------------------------------------------------------------------
template<int BM, int BN, int BK>
__global__ __launch_bounds__(256) void gemm_nt(const float* __restrict__ A,
                                               const float* __restrict__ B,
                                               float* __restrict__ C,
                                               int M, int N, int K)
{
    __shared__ float As[BK][BM + 4];
    __shared__ float Bs[BK][BN + 4];

    const int bm  = blockIdx.y * BM;
    const int bn  = blockIdx.x * BN;
    const int tid = threadIdx.x;
    const int tm  = tid >> 4;      // 0..15
    const int tn  = tid & 15;      // 0..15

    // loader mapping: 128 rows x 8 k per matrix per k-step; 4 floats/thread
    const int lrow = tid >> 1;          // 0..127
    const int lk4  = (tid & 1) * 4;     // 0 or 4

    const float* Ap = A + (size_t)(bm + lrow) * K + lk4;
    const float* Bp = B + (size_t)(bn + lrow) * K + lk4;

    float acc[8][8] = {};

    for (int k0 = 0; k0 < K; k0 += BK) {
        float4 av = *(const float4*)(Ap + k0);
        float4 bv = *(const float4*)(Bp + k0);
        As[lk4 + 0][lrow] = av.x; As[lk4 + 1][lrow] = av.y;
        As[lk4 + 2][lrow] = av.z; As[lk4 + 3][lrow] = av.w;
        Bs[lk4 + 0][lrow] = bv.x; Bs[lk4 + 1][lrow] = bv.y;
        Bs[lk4 + 2][lrow] = bv.z; Bs[lk4 + 3][lrow] = bv.w;
        __syncthreads();

#pragma unroll
        for (int kk = 0; kk < BK; kk++) {
            float a[8], b[8];
            *(float4*)&a[0] = *(const float4*)&As[kk][tm * 8];
            *(float4*)&a[4] = *(const float4*)&As[kk][tm * 8 + 4];
            *(float4*)&b[0] = *(const float4*)&Bs[kk][tn * 8];
            *(float4*)&b[4] = *(const float4*)&Bs[kk][tn * 8 + 4];
#pragma unroll
            for (int i = 0; i < 8; i++)
#pragma unroll
                for (int j = 0; j < 8; j++)
                    acc[i][j] += a[i] * b[j];
        }
        __syncthreads();
    }

#pragma unroll
    for (int i = 0; i < 8; i++) {
        float* crow = C + (size_t)(bm + tm * 8 + i) * N + bn + tn * 8;
#pragma unroll
        for (int j = 0; j < 8; j += 4) {
            float4 v = make_float4(acc[i][j], acc[i][j+1], acc[i][j+2], acc[i][j+3]);
            *(float4*)(crow + j) = v;
        }
    }
}

// ---------------------------------------------------------------------------
// Depthwise causal conv (K=4) + bias + SiLU.
// xr: (B*S, 4096), first INNER cols are x_ssm. out x_conv: (B*S, INNER)
// ---------------------------------------------------------------------------
__global__ __launch_bounds__(256) void conv_silu_kernel(
        const float* __restrict__ xr,
        const float* __restrict__ conv_w,   // (INNER, 1, 4)
        const float* __restrict__ conv_b,   // (INNER)
        float* __restrict__ x_conv)         // (B*S, INNER)
{
    int idx = blockIdx.x * 256 + threadIdx.x;       // over B*S*INNER
    int c  = idx & (INNER - 1);
    int sb = idx >> 11;            // b*S + s
    int s  = sb & (SEQ - 1);
    int b  = sb >> 11;

    float acc = conv_b[c];
    const float* wr = conv_w + c * CONV_KK;
#pragma unroll
    for (int k = 0; k < CONV_KK; k++) {
        int ss = s - (CONV_KK - 1) + k;
        if (ss >= 0) {
            acc += wr[k] * xr[((size_t)(b * SEQ + ss)) * N1 + c];
        }
    }
    // SiLU
    x_conv[(size_t)sb * INNER + c] = acc * sigmoidf_(acc);
}

// ---------------------------------------------------------------------------
// Sequential selective scan, fused with gating epilogue.
// 16 lanes per (b, channel): lane = state index. 256 threads = 16 channels.
// y_full[b,s,c] = (x_conv * sum_state(h)) * silu(res) + D[c]*x_conv
// ---------------------------------------------------------------------------
__global__ __launch_bounds__(256) void scan_kernel(
        const float* __restrict__ x_conv,   // (B*S, INNER)
        const float* __restrict__ xr,       // (B*S, 4096) -> res at col INNER+c
        const float* __restrict__ A_log,    // (INNER, STATE)
        const float* __restrict__ Dv,       // (INNER)
        float* __restrict__ y_full)         // (B*S, INNER)
{
    const int tid = threadIdx.x;
    const int st  = tid & 15;          // state
    const int cg  = tid >> 4;          // channel within block (0..15)
    const int gch = blockIdx.x * 16 + cg;   // 0 .. B*INNER-1
    const int b   = gch >> 11;
    const int c   = gch & (INNER - 1);

    const float Aneg = -expf(A_log[c * STATE_DIM + st]);
    const float Dc   = Dv[c];

    const float* xcp  = x_conv + (size_t)b * SEQ * INNER + c;
    const float* resp = xr     + (size_t)b * SEQ * N1 + INNER + c;
    float*       yp   = y_full + (size_t)b * SEQ * INNER + c;

    float h = 0.f;
    for (int s = 0; s < SEQ; s++) {
        float xc    = xcp[(size_t)s * INNER];
        float delta = softplusf(xc);
        float a     = expf(delta * Aneg);
        float bx    = xc * xc;
        h = a * h + bx;

        float sum = h;
        sum += __shfl_xor(sum, 1, 16);
        sum += __shfl_xor(sum, 2, 16);
        sum += __shfl_xor(sum, 4, 16);
        sum += __shfl_xor(sum, 8, 16);

        if (st == 0) {
            float r  = resp[(size_t)s * N1];
            float y  = xc * sum * (r * sigmoidf_(r)) + Dc * xc;
            yp[(size_t)s * INNER] = y;
        }
    }
}

// ---------------------------------------------------------------------------
extern "C" void kernel_launch(void* const* d_in, const int* in_sizes, int n_in,
                              void* d_out, int out_size, void* d_ws, size_t ws_size,
                              hipStream_t stream)
{
    const float* x      = (const float*)d_in[0];   // (B,S,1024)
    const float* W_in   = (const float*)d_in[1];   // (4096,1024)
    const float* conv_w = (const float*)d_in[2];   // (2048,1,4)
    const float* conv_b = (const float*)d_in[3];   // (2048)
    const float* A_log  = (const float*)d_in[4];   // (2048,16)
    const float* Dv     = (const float*)d_in[5];   // (2048)
    const float* W_out  = (const float*)d_in[6];   // (1024,2048)
    float* out = (float*)d_out;                    // (B,S,1024) f32

    // workspace layout (floats)
    float* xr     = (float*)d_ws;                           // 4096*4096
    float* x_conv = xr + (size_t)M_TOT * N1;                // 4096*2048
    float* y_full = x_conv + (size_t)M_TOT * INNER;         // 4096*2048

    // 1) xr = x @ W_in.T   (4096 x 4096, K=1024)
    gemm_nt<128,128,8><<<dim3(N1/128, M_TOT/128), 256, 0, stream>>>(
        x, W_in, xr, M_TOT, N1, K1);

    // 2) depthwise causal conv + SiLU
    conv_silu_kernel<<<(M_TOT * INNER) / 256, 256, 0, stream>>>(
        xr, conv_w, conv_b, x_conv);

    // 3) selective scan + gating epilogue
    scan_kernel<<<(BATCH * INNER) / 16, 256, 0, stream>>>(
        x_conv, xr, A_log, Dv, y_full);

    // 4) out = y_full @ W_out.T  (4096 x 1024, K=2048)
    gemm_nt<128,128,8><<<dim3(N2/128, M_TOT/128), 256, 0, stream>>>(
        y_full, W_out, out, M_TOT, N2, K2);
}

// Round 2
// 1139.356 us; speedup vs baseline: 2.5273x; 2.5273x over previous
//
#include <hip/hip_runtime.h>
#include <hip/hip_bf16.h>
#include <math.h>

// Problem constants (from reference)
#define INPUT_DIM 1024
#define STATE_DIM 16
#define CONV_KK   4
#define INNER     2048          // INPUT_DIM * EXPAND
#define BATCH     2
#define SEQ       2048
#define M_TOT     (BATCH*SEQ)   // 4096
#define N1        (2*INNER)     // 4096
#define K1        INPUT_DIM     // 1024
#define N2        INPUT_DIM     // 1024
#define K2        INNER         // 2048
#define NCHUNK    16
#define CLEN      (SEQ/NCHUNK)  // 128

// ---- fast transcendentals (threshold is 1.16e-2; these are ~1e-6 rel) ----
__device__ __forceinline__ float fast_softplus(float x) {
    // log(1 + e^x); for large x it is x (exp overflows -> guard)
    return x > 20.f ? x : __logf(1.f + __expf(x));
}
__device__ __forceinline__ float fast_silu(float x) {
    return x * __builtin_amdgcn_rcpf(1.f + __expf(-x));
}

// ---------------------------------------------------------------------------
// Tiled f32 GEMM, NT form: C[m][n] = sum_k A[m*K+k] * B[n*K+k]
// ---------------------------------------------------------------------------
template<int BM, int BN, int BK>
__global__ __launch_bounds__(256) void gemm_nt(const float* __restrict__ A,
                                               const float* __restrict__ B,
                                               float* __restrict__ C,
                                               int M, int N, int K)
{
    __shared__ float As[BK][BM + 4];
    __shared__ float Bs[BK][BN + 4];

    const int bm  = blockIdx.y * BM;
    const int bn  = blockIdx.x * BN;
    const int tid = threadIdx.x;
    const int tm  = tid >> 4;      // 0..15
    const int tn  = tid & 15;      // 0..15

    const int lrow = tid >> 1;          // 0..127
    const int lk4  = (tid & 1) * 4;     // 0 or 4

    const float* Ap = A + (size_t)(bm + lrow) * K + lk4;
    const float* Bp = B + (size_t)(bn + lrow) * K + lk4;

    float acc[8][8] = {};

    for (int k0 = 0; k0 < K; k0 += BK) {
        float4 av = *(const float4*)(Ap + k0);
        float4 bv = *(const float4*)(Bp + k0);
        As[lk4 + 0][lrow] = av.x; As[lk4 + 1][lrow] = av.y;
        As[lk4 + 2][lrow] = av.z; As[lk4 + 3][lrow] = av.w;
        Bs[lk4 + 0][lrow] = bv.x; Bs[lk4 + 1][lrow] = bv.y;
        Bs[lk4 + 2][lrow] = bv.z; Bs[lk4 + 3][lrow] = bv.w;
        __syncthreads();

#pragma unroll
        for (int kk = 0; kk < BK; kk++) {
            float a[8], b[8];
            *(float4*)&a[0] = *(const float4*)&As[kk][tm * 8];
            *(float4*)&a[4] = *(const float4*)&As[kk][tm * 8 + 4];
            *(float4*)&b[0] = *(const float4*)&Bs[kk][tn * 8];
            *(float4*)&b[4] = *(const float4*)&Bs[kk][tn * 8 + 4];
#pragma unroll
            for (int i = 0; i < 8; i++)
#pragma unroll
                for (int j = 0; j < 8; j++)
                    acc[i][j] += a[i] * b[j];
        }
        __syncthreads();
    }

#pragma unroll
    for (int i = 0; i < 8; i++) {
        float* crow = C + (size_t)(bm + tm * 8 + i) * N + bn + tn * 8;
#pragma unroll
        for (int j = 0; j < 8; j += 4) {
            float4 v = make_float4(acc[i][j], acc[i][j+1], acc[i][j+2], acc[i][j+3]);
            *(float4*)(crow + j) = v;
        }
    }
}

// ---------------------------------------------------------------------------
// Depthwise causal conv (K=4) + bias + SiLU.
// ---------------------------------------------------------------------------
__global__ __launch_bounds__(256) void conv_silu_kernel(
        const float* __restrict__ xr,
        const float* __restrict__ conv_w,   // (INNER, 1, 4)
        const float* __restrict__ conv_b,   // (INNER)
        float* __restrict__ x_conv)         // (B*S, INNER)
{
    int idx = blockIdx.x * 256 + threadIdx.x;       // over B*S*INNER
    int c  = idx & (INNER - 1);
    int sb = idx >> 11;            // b*S + s
    int s  = sb & (SEQ - 1);
    int b  = sb >> 11;

    float acc = conv_b[c];
    const float* wr = conv_w + c * CONV_KK;
#pragma unroll
    for (int k = 0; k < CONV_KK; k++) {
        int ss = s - (CONV_KK - 1) + k;
        if (ss >= 0) {
            acc += wr[k] * xr[((size_t)(b * SEQ + ss)) * N1 + c];
        }
    }
    x_conv[(size_t)sb * INNER + c] = fast_silu(acc) * 1.0f;
}

// ---------------------------------------------------------------------------
// Chunked scan, pass A: per-(b,chunk,c) local end-state (h0=0) and sum(delta).
// 16 lanes per group (lane = state). 16 groups per block.
// gid = (b, chunk, c) with c fastest (4 consecutive c per wave -> one 16B seg).
// ---------------------------------------------------------------------------
__global__ __launch_bounds__(256) void scan_chunk_stats(
        const float* __restrict__ x_conv,   // (B*S, INNER)
        const float* __restrict__ A_log,    // (INNER, 16)
        float* __restrict__ Hc,             // [B][NCHUNK][INNER][16]
        float* __restrict__ Dsum)           // [B][NCHUNK][INNER]
{
    const int tid = threadIdx.x;
    const int st  = tid & 15;
    const int g   = tid >> 4;
    const int gid = blockIdx.x * 16 + g;
    const int c     = gid & (INNER - 1);
    const int chunk = (gid >> 11) & (NCHUNK - 1);
    const int b     = gid >> 15;

    const float Aneg = -__expf(A_log[c * STATE_DIM + st]);
    const float* xcp = x_conv + ((size_t)(b * SEQ + chunk * CLEN)) * INNER + c;

    float h = 0.f, dsum = 0.f;
    for (int s = 0; s < CLEN; s++) {
        float xc    = xcp[(size_t)s * INNER];
        float delta = fast_softplus(xc);
        dsum += delta;
        float a = __expf(delta * Aneg);
        h = a * h + xc * xc;
    }
    size_t base = ((size_t)b * NCHUNK + chunk) * INNER + c;
    Hc[base * 16 + st] = h;
    if (st == 0) Dsum[base] = dsum;
}

// ---------------------------------------------------------------------------
// Pass B: carry propagation across the 16 chunks. One thread per (b,c,st).
// IN-PLACE: Hc[j] is read, then overwritten with the chunk's INITIAL state.
// ---------------------------------------------------------------------------
__global__ __launch_bounds__(256) void scan_carry(
        float* __restrict__ Hc,             // in: end states; out: init states
        const float* __restrict__ Dsum,
        const float* __restrict__ A_log)
{
    const int tid = blockIdx.x * 256 + threadIdx.x;   // (b, c, st), st fastest
    const int st = tid & 15;
    const int c  = (tid >> 4) & (INNER - 1);
    const int b  = tid >> 15;

    const float Aneg = -__expf(A_log[c * STATE_DIM + st]);
    float carry = 0.f;
    for (int j = 0; j < NCHUNK; j++) {
        size_t base = ((size_t)b * NCHUNK + j) * INNER + c;
        float hend = Hc[base * 16 + st];
        float P    = __expf(Dsum[base] * Aneg);
        Hc[base * 16 + st] = carry;        // becomes this chunk's init state
        carry = P * carry + hend;
    }
}

// ---------------------------------------------------------------------------
// Pass C: recompute chunk scan from correct init state + gating epilogue.
// ---------------------------------------------------------------------------
__global__ __launch_bounds__(256) void scan_apply(
        const float* __restrict__ x_conv,   // (B*S, INNER)
        const float* __restrict__ xr,       // (B*S, 4096): res at col INNER+c
        const float* __restrict__ Cinit,    // [B][NCHUNK][INNER][16]
        const float* __restrict__ A_log,
        const float* __restrict__ Dv,
        float* __restrict__ y_full)         // (B*S, INNER)
{
    const int tid = threadIdx.x;
    const int st  = tid & 15;
    const int g   = tid >> 4;
    const int gid = blockIdx.x * 16 + g;
    const int c     = gid & (INNER - 1);
    const int chunk = (gid >> 11) & (NCHUNK - 1);
    const int b     = gid >> 15;

    const float Aneg = -__expf(A_log[c * STATE_DIM + st]);
    const float Dc   = Dv[c];
    const size_t row0 = (size_t)(b * SEQ + chunk * CLEN);
    const float* xcp  = x_conv + row0 * INNER + c;
    const float* resp = xr     + row0 * N1 + INNER + c;
    float*       yp   = y_full + row0 * INNER + c;

    size_t base = ((size_t)b * NCHUNK + chunk) * INNER + c;
    float h = Cinit[base * 16 + st];

    for (int s = 0; s < CLEN; s++) {
        float xc    = xcp[(size_t)s * INNER];
        float delta = fast_softplus(xc);
        float a     = __expf(delta * Aneg);
        h = a * h + xc * xc;

        float sum = h;
        sum += __shfl_xor(sum, 1, 16);
        sum += __shfl_xor(sum, 2, 16);
        sum += __shfl_xor(sum, 4, 16);
        sum += __shfl_xor(sum, 8, 16);

        if (st == 0) {
            float r = resp[(size_t)s * N1];
            yp[(size_t)s * INNER] = xc * sum * fast_silu(r) + Dc * xc;
        }
    }
}

// ---------------------------------------------------------------------------
extern "C" void kernel_launch(void* const* d_in, const int* in_sizes, int n_in,
                              void* d_out, int out_size, void* d_ws, size_t ws_size,
                              hipStream_t stream)
{
    const float* x      = (const float*)d_in[0];   // (B,S,1024)
    const float* W_in   = (const float*)d_in[1];   // (4096,1024)
    const float* conv_w = (const float*)d_in[2];   // (2048,1,4)
    const float* conv_b = (const float*)d_in[3];   // (2048)
    const float* A_log  = (const float*)d_in[4];   // (2048,16)
    const float* Dv     = (const float*)d_in[5];   // (2048)
    const float* W_out  = (const float*)d_in[6];   // (1024,2048)
    float* out = (float*)d_out;                    // (B,S,1024) f32

    // workspace layout (floats): 64 + 32 + 32 + 4 + 0.25 MB = 132.25 MB
    float* xr     = (float*)d_ws;                           // 4096*4096
    float* x_conv = xr + (size_t)M_TOT * N1;                // 4096*2048
    float* y_full = x_conv + (size_t)M_TOT * INNER;         // 4096*2048
    float* Hc     = y_full + (size_t)M_TOT * INNER;         // 2*16*2048*16
    float* Dsum   = Hc + (size_t)BATCH * NCHUNK * INNER * STATE_DIM; // 2*16*2048

    // 1) xr = x @ W_in.T   (4096 x 4096, K=1024)
    gemm_nt<128,128,8><<<dim3(N1/128, M_TOT/128), 256, 0, stream>>>(
        x, W_in, xr, M_TOT, N1, K1);

    // 2) depthwise causal conv + SiLU
    conv_silu_kernel<<<(M_TOT * INNER) / 256, 256, 0, stream>>>(
        xr, conv_w, conv_b, x_conv);

    // 3) chunked selective scan
    scan_chunk_stats<<<(BATCH * INNER * NCHUNK) / 16, 256, 0, stream>>>(
        x_conv, A_log, Hc, Dsum);
    scan_carry<<<(BATCH * INNER * STATE_DIM) / 256, 256, 0, stream>>>(
        Hc, Dsum, A_log);
    scan_apply<<<(BATCH * INNER * NCHUNK) / 16, 256, 0, stream>>>(
        x_conv, xr, Hc, A_log, Dv, y_full);

    // 4) out = y_full @ W_out.T  (4096 x 1024, K=2048)
    gemm_nt<128,128,8><<<dim3(N2/128, M_TOT/128), 256, 0, stream>>>(
        y_full, W_out, out, M_TOT, N2, K2);
}

// Round 3
// 544.488 us; speedup vs baseline: 5.2885x; 2.0925x over previous
//
#include <hip/hip_runtime.h>
#include <hip/hip_bf16.h>
#include <math.h>

// Problem constants (from reference)
#define INPUT_DIM 1024
#define STATE_DIM 16
#define CONV_KK   4
#define INNER     2048          // INPUT_DIM * EXPAND
#define BATCH     2
#define SEQ       2048
#define M_TOT     (BATCH*SEQ)   // 4096
#define N1        (2*INNER)     // 4096
#define K1        INPUT_DIM     // 1024
#define N2        INPUT_DIM     // 1024
#define K2        INNER         // 2048
#define NCHUNK    16
#define CLEN      (SEQ/NCHUNK)  // 128

typedef __attribute__((ext_vector_type(8))) short short8;
typedef __attribute__((ext_vector_type(4))) float f32x4;
typedef unsigned short ushort;

// ---- fast transcendentals (threshold is 1.16e-2; these are ~1e-6 rel) ----
__device__ __forceinline__ float fast_softplus(float x) {
    return x > 20.f ? x : __logf(1.f + __expf(x));
}
__device__ __forceinline__ float fast_silu(float x) {
    return x * __builtin_amdgcn_rcpf(1.f + __expf(-x));
}
__device__ __forceinline__ ushort f2bf(float f) {
    unsigned u = __float_as_uint(f);
    u = (u + 0x7FFF + ((u >> 16) & 1)) >> 16;   // RNE
    return (ushort)u;
}

// ---------------------------------------------------------------------------
// f32 -> bf16 convert, 8 floats / thread
// ---------------------------------------------------------------------------
__global__ __launch_bounds__(256) void cvt_bf16_kernel(
        const float* __restrict__ in, ushort* __restrict__ out, int n8)
{
    int i = blockIdx.x * 256 + threadIdx.x;
    if (i >= n8) return;
    const float4* p = (const float4*)in + (size_t)i * 2;
    float4 v0 = p[0], v1 = p[1];
    ushort u[8] = { f2bf(v0.x), f2bf(v0.y), f2bf(v0.z), f2bf(v0.w),
                    f2bf(v1.x), f2bf(v1.y), f2bf(v1.z), f2bf(v1.w) };
    *(short8*)(out + (size_t)i * 8) = *(short8*)u;
}

// ---------------------------------------------------------------------------
// bf16 MFMA GEMM, NT form: C[m][n] = sum_k A[m*K+k] * B[n*K+k], C in f32.
// m97 structure: BK=32, global_load_lds width-16 staging, 2-barrier K-loop.
// 4 waves arranged WROWS x WCOLS; per-wave tile (BM/WROWS) x (BN/WCOLS).
// ---------------------------------------------------------------------------
template<int BM, int BN, int WROWS, int WCOLS>
__global__ __launch_bounds__(256) void gemm_bf16_nt(
        const ushort* __restrict__ A, const ushort* __restrict__ B,
        float* __restrict__ C, int M, int N, int K)
{
    constexpr int MR = BM / WROWS / 16;    // m-frags per wave
    constexpr int NR = BN / WCOLS / 16;    // n-frags per wave
    __shared__ ushort As[BM][32];
    __shared__ ushort Bs[BN][32];

    const int tid  = threadIdx.x;
    const int w    = tid >> 6;
    const int lane = tid & 63;
    const int bm   = blockIdx.y * BM;
    const int bn   = blockIdx.x * BN;
    const int wm0  = (w / WCOLS) * (BM / WROWS);
    const int wn0  = (w % WCOLS) * (BN / WCOLS);

    const int srow = lane >> 2;         // 0..15, row within 16-row chunk
    const int scol = (lane & 3) * 8;    // k element offset

    f32x4 acc[MR][NR] = {};

    for (int k0 = 0; k0 < K; k0 += 32) {
        __syncthreads();
        // stage A tile (BM x 32) : 16-row chunks, wave-uniform LDS base
#pragma unroll
        for (int r0 = w * 16; r0 < BM; r0 += 64) {
            const ushort* ga = A + (size_t)(bm + r0 + srow) * K + k0 + scol;
            __builtin_amdgcn_global_load_lds(
                (const __attribute__((address_space(1))) void*)ga,
                (__attribute__((address_space(3))) void*)&As[r0][0], 16, 0, 0);
        }
#pragma unroll
        for (int r0 = w * 16; r0 < BN; r0 += 64) {
            const ushort* gb = B + (size_t)(bn + r0 + srow) * K + k0 + scol;
            __builtin_amdgcn_global_load_lds(
                (const __attribute__((address_space(1))) void*)gb,
                (__attribute__((address_space(3))) void*)&Bs[r0][0], 16, 0, 0);
        }
        __syncthreads();

        short8 a[MR], b[NR];
#pragma unroll
        for (int i = 0; i < MR; i++)
            a[i] = *(const short8*)&As[wm0 + i * 16 + (lane & 15)][(lane >> 4) * 8];
#pragma unroll
        for (int j = 0; j < NR; j++)
            b[j] = *(const short8*)&Bs[wn0 + j * 16 + (lane & 15)][(lane >> 4) * 8];
#pragma unroll
        for (int i = 0; i < MR; i++)
#pragma unroll
            for (int j = 0; j < NR; j++)
                acc[i][j] = __builtin_amdgcn_mfma_f32_16x16x32_bf16(
                    a[i], b[j], acc[i][j], 0, 0, 0);
    }

    // epilogue: D row=(lane>>4)*4+r, col=lane&15  [verified m89/m91]
#pragma unroll
    for (int i = 0; i < MR; i++)
#pragma unroll
        for (int j = 0; j < NR; j++)
#pragma unroll
            for (int r = 0; r < 4; r++) {
                int row = bm + wm0 + i * 16 + (lane >> 4) * 4 + r;
                int col = bn + wn0 + j * 16 + (lane & 15);
                C[(size_t)row * N + col] = acc[i][j][r];
            }
}

// ---------------------------------------------------------------------------
// Depthwise causal conv (K=4) + bias + SiLU.
// ---------------------------------------------------------------------------
__global__ __launch_bounds__(256) void conv_silu_kernel(
        const float* __restrict__ xr,
        const float* __restrict__ conv_w,   // (INNER, 1, 4)
        const float* __restrict__ conv_b,   // (INNER)
        float* __restrict__ x_conv)         // (B*S, INNER)
{
    int idx = blockIdx.x * 256 + threadIdx.x;
    int c  = idx & (INNER - 1);
    int sb = idx >> 11;
    int s  = sb & (SEQ - 1);
    int b  = sb >> 11;

    float acc = conv_b[c];
    const float* wr = conv_w + c * CONV_KK;
#pragma unroll
    for (int k = 0; k < CONV_KK; k++) {
        int ss = s - (CONV_KK - 1) + k;
        if (ss >= 0) {
            acc += wr[k] * xr[((size_t)(b * SEQ + ss)) * N1 + c];
        }
    }
    x_conv[(size_t)sb * INNER + c] = fast_silu(acc);
}

// ---------------------------------------------------------------------------
// Chunked scan, pass A: local end-state (h0=0) + sum(delta) per chunk.
// ---------------------------------------------------------------------------
__global__ __launch_bounds__(256) void scan_chunk_stats(
        const float* __restrict__ x_conv,
        const float* __restrict__ A_log,
        float* __restrict__ Hc,             // [B][NCHUNK][INNER][16]
        float* __restrict__ Dsum)           // [B][NCHUNK][INNER]
{
    const int tid = threadIdx.x;
    const int st  = tid & 15;
    const int g   = tid >> 4;
    const int gid = blockIdx.x * 16 + g;
    const int c     = gid & (INNER - 1);
    const int chunk = (gid >> 11) & (NCHUNK - 1);
    const int b     = gid >> 15;

    const float Aneg = -__expf(A_log[c * STATE_DIM + st]);
    const float* xcp = x_conv + ((size_t)(b * SEQ + chunk * CLEN)) * INNER + c;

    float h = 0.f, dsum = 0.f;
    for (int s = 0; s < CLEN; s++) {
        float xc    = xcp[(size_t)s * INNER];
        float delta = fast_softplus(xc);
        dsum += delta;
        float a = __expf(delta * Aneg);
        h = a * h + xc * xc;
    }
    size_t base = ((size_t)b * NCHUNK + chunk) * INNER + c;
    Hc[base * 16 + st] = h;
    if (st == 0) Dsum[base] = dsum;
}

// ---------------------------------------------------------------------------
// Pass B: carry propagation across 16 chunks; Hc becomes init states.
// ---------------------------------------------------------------------------
__global__ __launch_bounds__(256) void scan_carry(
        float* __restrict__ Hc,
        const float* __restrict__ Dsum,
        const float* __restrict__ A_log)
{
    const int tid = blockIdx.x * 256 + threadIdx.x;
    const int st = tid & 15;
    const int c  = (tid >> 4) & (INNER - 1);
    const int b  = tid >> 15;

    const float Aneg = -__expf(A_log[c * STATE_DIM + st]);
    float carry = 0.f;
    for (int j = 0; j < NCHUNK; j++) {
        size_t base = ((size_t)b * NCHUNK + j) * INNER + c;
        float hend = Hc[base * 16 + st];
        float P    = __expf(Dsum[base] * Aneg);
        Hc[base * 16 + st] = carry;
        carry = P * carry + hend;
    }
}

// ---------------------------------------------------------------------------
// Pass C: recompute chunk scan from init state + gating; OUTPUT IS BF16.
// ---------------------------------------------------------------------------
__global__ __launch_bounds__(256) void scan_apply(
        const float* __restrict__ x_conv,
        const float* __restrict__ xr,       // res at col INNER+c
        const float* __restrict__ Cinit,    // [B][NCHUNK][INNER][16]
        const float* __restrict__ A_log,
        const float* __restrict__ Dv,
        ushort* __restrict__ y_bf)          // (B*S, INNER) bf16
{
    const int tid = threadIdx.x;
    const int st  = tid & 15;
    const int g   = tid >> 4;
    const int gid = blockIdx.x * 16 + g;
    const int c     = gid & (INNER - 1);
    const int chunk = (gid >> 11) & (NCHUNK - 1);
    const int b     = gid >> 15;

    const float Aneg = -__expf(A_log[c * STATE_DIM + st]);
    const float Dc   = Dv[c];
    const size_t row0 = (size_t)(b * SEQ + chunk * CLEN);
    const float* xcp  = x_conv + row0 * INNER + c;
    const float* resp = xr     + row0 * N1 + INNER + c;
    ushort*      yp   = y_bf   + row0 * INNER + c;

    size_t base = ((size_t)b * NCHUNK + chunk) * INNER + c;
    float h = Cinit[base * 16 + st];

    for (int s = 0; s < CLEN; s++) {
        float xc    = xcp[(size_t)s * INNER];
        float delta = fast_softplus(xc);
        float a     = __expf(delta * Aneg);
        h = a * h + xc * xc;

        float sum = h;
        sum += __shfl_xor(sum, 1, 16);
        sum += __shfl_xor(sum, 2, 16);
        sum += __shfl_xor(sum, 4, 16);
        sum += __shfl_xor(sum, 8, 16);

        if (st == 0) {
            float r = resp[(size_t)s * N1];
            yp[(size_t)s * INNER] = f2bf(xc * sum * fast_silu(r) + Dc * xc);
        }
    }
}

// ---------------------------------------------------------------------------
extern "C" void kernel_launch(void* const* d_in, const int* in_sizes, int n_in,
                              void* d_out, int out_size, void* d_ws, size_t ws_size,
                              hipStream_t stream)
{
    const float* x      = (const float*)d_in[0];
    const float* W_in   = (const float*)d_in[1];
    const float* conv_w = (const float*)d_in[2];
    const float* conv_b = (const float*)d_in[3];
    const float* A_log  = (const float*)d_in[4];
    const float* Dv     = (const float*)d_in[5];
    const float* W_out  = (const float*)d_in[6];
    float* out = (float*)d_out;

    // workspace layout (bytes)
    char* ws = (char*)d_ws;
    float*  xr      = (float*)ws;                 ws += (size_t)M_TOT * N1 * 4;      // 64 MB
    float*  x_conv  = (float*)ws;                 ws += (size_t)M_TOT * INNER * 4;   // 32 MB
    float*  Hc      = (float*)ws;                 ws += (size_t)BATCH * NCHUNK * INNER * STATE_DIM * 4; // 4 MB
    float*  Dsum    = (float*)ws;                 ws += (size_t)BATCH * NCHUNK * INNER * 4;             // 256 KB
    ushort* x_bf    = (ushort*)ws;                ws += (size_t)M_TOT * K1 * 2;      // 8 MB
    ushort* Win_bf  = (ushort*)ws;                ws += (size_t)N1 * K1 * 2;         // 8 MB
    ushort* Wout_bf = (ushort*)ws;                ws += (size_t)N2 * K2 * 2;         // 4 MB
    ushort* y_bf    = (ushort*)ws;                ws += (size_t)M_TOT * INNER * 2;   // 16 MB

    // 0) f32 -> bf16 converts
    cvt_bf16_kernel<<<(M_TOT * K1 / 8) / 256, 256, 0, stream>>>(x, x_bf, M_TOT * K1 / 8);
    cvt_bf16_kernel<<<(N1 * K1 / 8) / 256, 256, 0, stream>>>(W_in, Win_bf, N1 * K1 / 8);
    cvt_bf16_kernel<<<(N2 * K2 / 8) / 256, 256, 0, stream>>>(W_out, Wout_bf, N2 * K2 / 8);

    // 1) xr = x @ W_in.T   (4096 x 4096, K=1024) -- bf16 MFMA
    gemm_bf16_nt<128,128,2,2><<<dim3(N1/128, M_TOT/128), 256, 0, stream>>>(
        x_bf, Win_bf, xr, M_TOT, N1, K1);

    // 2) depthwise causal conv + SiLU
    conv_silu_kernel<<<(M_TOT * INNER) / 256, 256, 0, stream>>>(
        xr, conv_w, conv_b, x_conv);

    // 3) chunked selective scan (y emitted as bf16)
    scan_chunk_stats<<<(BATCH * INNER * NCHUNK) / 16, 256, 0, stream>>>(
        x_conv, A_log, Hc, Dsum);
    scan_carry<<<(BATCH * INNER * STATE_DIM) / 256, 256, 0, stream>>>(
        Hc, Dsum, A_log);
    scan_apply<<<(BATCH * INNER * NCHUNK) / 16, 256, 0, stream>>>(
        x_conv, xr, Hc, A_log, Dv, y_bf);

    // 4) out = y @ W_out.T  (4096 x 1024, K=2048) -- bf16 MFMA
    gemm_bf16_nt<128,64,2,2><<<dim3(N2/64, M_TOT/128), 256, 0, stream>>>(
        y_bf, Wout_bf, out, M_TOT, N2, K2);
}

// Round 5
// 258.446 us; speedup vs baseline: 11.1416x; 2.1068x over previous
//
#include <hip/hip_runtime.h>
#include <hip/hip_bf16.h>
#include <math.h>

// Problem constants (from reference)
#define INPUT_DIM 1024
#define STATE_DIM 16
#define CONV_KK   4
#define INNER     2048          // INPUT_DIM * EXPAND
#define BATCH     2
#define SEQ       2048
#define M_TOT     (BATCH*SEQ)   // 4096
#define N1        (2*INNER)     // 4096
#define K1        INPUT_DIM     // 1024
#define N2        INPUT_DIM     // 1024
#define K2        INNER         // 2048
#define NCHUNK    64
#define CLEN      (SEQ/NCHUNK)  // 32

typedef __attribute__((ext_vector_type(8))) short short8;
typedef __attribute__((ext_vector_type(4))) float f32x4;
typedef unsigned short ushort;

// ---- fast transcendentals (threshold is 1.16e-2; these are ~1e-6 rel) ----
__device__ __forceinline__ float fast_softplus(float x) {
    return x > 20.f ? x : __logf(1.f + __expf(x));
}
__device__ __forceinline__ float fast_silu(float x) {
    return x * __builtin_amdgcn_rcpf(1.f + __expf(-x));
}
__device__ __forceinline__ ushort f2bf(float f) {
    unsigned u = __float_as_uint(f);
    u = (u + 0x7FFF + ((u >> 16) & 1)) >> 16;   // RNE
    return (ushort)u;
}

// ---------------------------------------------------------------------------
// f32 -> bf16 convert, 8 floats / thread
// ---------------------------------------------------------------------------
__global__ __launch_bounds__(256) void cvt_bf16_kernel(
        const float* __restrict__ in, ushort* __restrict__ out, int n8)
{
    int i = blockIdx.x * 256 + threadIdx.x;
    if (i >= n8) return;
    const float4* p = (const float4*)in + (size_t)i * 2;
    float4 v0 = p[0], v1 = p[1];
    ushort u[8] = { f2bf(v0.x), f2bf(v0.y), f2bf(v0.z), f2bf(v0.w),
                    f2bf(v1.x), f2bf(v1.y), f2bf(v1.z), f2bf(v1.w) };
    *(short8*)(out + (size_t)i * 8) = *(short8*)u;
}

// ---------------------------------------------------------------------------
// bf16 MFMA GEMM, NT form (m97 structure). Unchanged from round 3.
// ---------------------------------------------------------------------------
template<int BM, int BN, int WROWS, int WCOLS>
__global__ __launch_bounds__(256) void gemm_bf16_nt(
        const ushort* __restrict__ A, const ushort* __restrict__ B,
        float* __restrict__ C, int M, int N, int K)
{
    constexpr int MR = BM / WROWS / 16;
    constexpr int NR = BN / WCOLS / 16;
    __shared__ ushort As[BM][32];
    __shared__ ushort Bs[BN][32];

    const int tid  = threadIdx.x;
    const int w    = tid >> 6;
    const int lane = tid & 63;
    const int bm   = blockIdx.y * BM;
    const int bn   = blockIdx.x * BN;
    const int wm0  = (w / WCOLS) * (BM / WROWS);
    const int wn0  = (w % WCOLS) * (BN / WCOLS);

    const int srow = lane >> 2;
    const int scol = (lane & 3) * 8;

    f32x4 acc[MR][NR] = {};

    for (int k0 = 0; k0 < K; k0 += 32) {
        __syncthreads();
#pragma unroll
        for (int r0 = w * 16; r0 < BM; r0 += 64) {
            const ushort* ga = A + (size_t)(bm + r0 + srow) * K + k0 + scol;
            __builtin_amdgcn_global_load_lds(
                (const __attribute__((address_space(1))) void*)ga,
                (__attribute__((address_space(3))) void*)&As[r0][0], 16, 0, 0);
        }
#pragma unroll
        for (int r0 = w * 16; r0 < BN; r0 += 64) {
            const ushort* gb = B + (size_t)(bn + r0 + srow) * K + k0 + scol;
            __builtin_amdgcn_global_load_lds(
                (const __attribute__((address_space(1))) void*)gb,
                (__attribute__((address_space(3))) void*)&Bs[r0][0], 16, 0, 0);
        }
        __syncthreads();

        short8 a[MR], b[NR];
#pragma unroll
        for (int i = 0; i < MR; i++)
            a[i] = *(const short8*)&As[wm0 + i * 16 + (lane & 15)][(lane >> 4) * 8];
#pragma unroll
        for (int j = 0; j < NR; j++)
            b[j] = *(const short8*)&Bs[wn0 + j * 16 + (lane & 15)][(lane >> 4) * 8];
#pragma unroll
        for (int i = 0; i < MR; i++)
#pragma unroll
            for (int j = 0; j < NR; j++)
                acc[i][j] = __builtin_amdgcn_mfma_f32_16x16x32_bf16(
                    a[i], b[j], acc[i][j], 0, 0, 0);
    }

#pragma unroll
    for (int i = 0; i < MR; i++)
#pragma unroll
        for (int j = 0; j < NR; j++)
#pragma unroll
            for (int r = 0; r < 4; r++) {
                int row = bm + wm0 + i * 16 + (lane >> 4) * 4 + r;
                int col = bn + wn0 + j * 16 + (lane & 15);
                C[(size_t)row * N + col] = acc[i][j][r];
            }
}

// ---------------------------------------------------------------------------
// Scan pass A (fused conv+SiLU): one thread per (b,chunk,c), 16 states in
// registers. Emits per-chunk end state (h0=0) and sum(delta).
// Hc layout: [B][NCHUNK][16][INNER] ; Dsum: [B][NCHUNK][INNER]
// ---------------------------------------------------------------------------
__global__ __launch_bounds__(256) void scan_stats_fused(
        const float* __restrict__ xr,       // (B*S, 4096)
        const float* __restrict__ conv_w,   // (INNER,1,4)
        const float* __restrict__ conv_b,   // (INNER)
        const float* __restrict__ A_log,    // (INNER,16)
        float* __restrict__ Hc,
        float* __restrict__ Dsum)
{
    const int gid = blockIdx.x * 256 + threadIdx.x;   // (b, chunk, c), c fastest
    const int c     = gid & (INNER - 1);
    const int chunk = (gid >> 11) & (NCHUNK - 1);
    const int b     = gid >> 17;

    const float4 w4  = *(const float4*)(conv_w + c * 4);
    const float bias = conv_b[c];

    float negA[16];
    {
        const float4* ap = (const float4*)(A_log + c * 16);
#pragma unroll
        for (int q = 0; q < 4; q++) {
            float4 v = ap[q];
            negA[q*4+0] = -__expf(v.x); negA[q*4+1] = -__expf(v.y);
            negA[q*4+2] = -__expf(v.z); negA[q*4+3] = -__expf(v.w);
        }
    }

    const int s0 = chunk * CLEN;
    const float* xp = xr + ((size_t)(b * SEQ + s0)) * N1 + c;

    float xm1 = 0.f, xm2 = 0.f, xm3 = 0.f;   // x[s0-1], x[s0-2], x[s0-3]
    if (s0 > 0) { xm1 = xp[-N1]; xm2 = xp[-2*N1]; xm3 = xp[-3*N1]; }

    float h[16] = {};
    float dsum = 0.f;
    for (int s = 0; s < CLEN; s++) {
        float x0  = xp[(size_t)s * N1];
        float acc = bias + w4.x*xm3 + w4.y*xm2 + w4.z*xm1 + w4.w*x0;
        xm3 = xm2; xm2 = xm1; xm1 = x0;
        float xc    = fast_silu(acc);
        float delta = fast_softplus(xc);
        dsum += delta;
        float bx = xc * xc;
#pragma unroll
        for (int st = 0; st < 16; st++)
            h[st] = __expf(delta * negA[st]) * h[st] + bx;
    }

    const size_t cb = (size_t)b * NCHUNK + chunk;
#pragma unroll
    for (int st = 0; st < 16; st++)
        Hc[(cb * 16 + st) * INNER + c] = h[st];
    Dsum[cb * INNER + c] = dsum;
}

// ---------------------------------------------------------------------------
// Pass B: carry propagation across NCHUNK chunks; Hc becomes init states.
// One thread per (b, st, c), c fastest.
// ---------------------------------------------------------------------------
__global__ __launch_bounds__(256) void scan_carry(
        float* __restrict__ Hc,
        const float* __restrict__ Dsum,
        const float* __restrict__ A_log)
{
    const int tid = blockIdx.x * 256 + threadIdx.x;
    const int c  = tid & (INNER - 1);
    const int st = (tid >> 11) & 15;
    const int b  = tid >> 15;

    const float negA = -__expf(A_log[c * STATE_DIM + st]);
    float carry = 0.f;
    for (int j = 0; j < NCHUNK; j++) {
        const size_t cb  = (size_t)b * NCHUNK + j;
        const size_t idx = (cb * 16 + st) * INNER + c;
        float hend = Hc[idx];
        float P    = __expf(Dsum[cb * INNER + c] * negA);
        Hc[idx] = carry;
        carry = P * carry + hend;
    }
}

// ---------------------------------------------------------------------------
// Pass C (fused conv+SiLU + scan + gating): recompute chunk from init state,
// emit y as bf16. One thread per (b,chunk,c), 16 states in registers.
// ---------------------------------------------------------------------------
__global__ __launch_bounds__(256) void scan_apply_fused(
        const float* __restrict__ xr,
        const float* __restrict__ conv_w,
        const float* __restrict__ conv_b,
        const float* __restrict__ A_log,
        const float* __restrict__ Dv,
        const float* __restrict__ Hc,       // init states
        ushort* __restrict__ y_bf)          // (B*S, INNER) bf16
{
    const int gid = blockIdx.x * 256 + threadIdx.x;
    const int c     = gid & (INNER - 1);
    const int chunk = (gid >> 11) & (NCHUNK - 1);
    const int b     = gid >> 17;

    const float4 w4  = *(const float4*)(conv_w + c * 4);
    const float bias = conv_b[c];
    const float Dc   = Dv[c];

    float negA[16];
    {
        const float4* ap = (const float4*)(A_log + c * 16);
#pragma unroll
        for (int q = 0; q < 4; q++) {
            float4 v = ap[q];
            negA[q*4+0] = -__expf(v.x); negA[q*4+1] = -__expf(v.y);
            negA[q*4+2] = -__expf(v.z); negA[q*4+3] = -__expf(v.w);
        }
    }

    const int s0 = chunk * CLEN;
    const size_t row0 = (size_t)(b * SEQ + s0);
    const float* xp = xr + row0 * N1 + c;
    const float* rp = xr + row0 * N1 + INNER + c;
    ushort*      yp = y_bf + row0 * INNER + c;

    float xm1 = 0.f, xm2 = 0.f, xm3 = 0.f;
    if (s0 > 0) { xm1 = xp[-N1]; xm2 = xp[-2*N1]; xm3 = xp[-3*N1]; }

    const size_t cb = (size_t)b * NCHUNK + chunk;
    float h[16];
#pragma unroll
    for (int st = 0; st < 16; st++)
        h[st] = Hc[(cb * 16 + st) * INNER + c];

    for (int s = 0; s < CLEN; s++) {
        float x0  = xp[(size_t)s * N1];
        float acc = bias + w4.x*xm3 + w4.y*xm2 + w4.z*xm1 + w4.w*x0;
        xm3 = xm2; xm2 = xm1; xm1 = x0;
        float xc    = fast_silu(acc);
        float delta = fast_softplus(xc);
        float bx    = xc * xc;
#pragma unroll
        for (int st = 0; st < 16; st++)
            h[st] = __expf(delta * negA[st]) * h[st] + bx;

        // pairwise state sum (register tree, no shuffles)
        float s01 = (h[0]+h[1]) + (h[2]+h[3]);
        float s23 = (h[4]+h[5]) + (h[6]+h[7]);
        float s45 = (h[8]+h[9]) + (h[10]+h[11]);
        float s67 = (h[12]+h[13]) + (h[14]+h[15]);
        float sum = (s01 + s23) + (s45 + s67);

        float r = rp[(size_t)s * N1];
        float y = xc * sum * fast_silu(r) + Dc * xc;
        yp[(size_t)s * INNER] = f2bf(y);
    }
}

// ---------------------------------------------------------------------------
extern "C" void kernel_launch(void* const* d_in, const int* in_sizes, int n_in,
                              void* d_out, int out_size, void* d_ws, size_t ws_size,
                              hipStream_t stream)
{
    const float* x      = (const float*)d_in[0];
    const float* W_in   = (const float*)d_in[1];
    const float* conv_w = (const float*)d_in[2];
    const float* conv_b = (const float*)d_in[3];
    const float* A_log  = (const float*)d_in[4];
    const float* Dv     = (const float*)d_in[5];
    const float* W_out  = (const float*)d_in[6];
    float* out = (float*)d_out;

    // workspace layout (bytes): 64+16+1+8+8+4+16 = 117 MB
    char* ws = (char*)d_ws;
    float*  xr      = (float*)ws;   ws += (size_t)M_TOT * N1 * 4;
    float*  Hc      = (float*)ws;   ws += (size_t)BATCH * NCHUNK * STATE_DIM * INNER * 4;
    float*  Dsum    = (float*)ws;   ws += (size_t)BATCH * NCHUNK * INNER * 4;
    ushort* x_bf    = (ushort*)ws;  ws += (size_t)M_TOT * K1 * 2;
    ushort* Win_bf  = (ushort*)ws;  ws += (size_t)N1 * K1 * 2;
    ushort* Wout_bf = (ushort*)ws;  ws += (size_t)N2 * K2 * 2;
    ushort* y_bf    = (ushort*)ws;  ws += (size_t)M_TOT * INNER * 2;

    // 0) f32 -> bf16 converts
    cvt_bf16_kernel<<<(M_TOT * K1 / 8) / 256, 256, 0, stream>>>(x, x_bf, M_TOT * K1 / 8);
    cvt_bf16_kernel<<<(N1 * K1 / 8) / 256, 256, 0, stream>>>(W_in, Win_bf, N1 * K1 / 8);
    cvt_bf16_kernel<<<(N2 * K2 / 8) / 256, 256, 0, stream>>>(W_out, Wout_bf, N2 * K2 / 8);

    // 1) xr = x @ W_in.T   (4096 x 4096, K=1024) -- bf16 MFMA
    gemm_bf16_nt<128,128,2,2><<<dim3(N1/128, M_TOT/128), 256, 0, stream>>>(
        x_bf, Win_bf, xr, M_TOT, N1, K1);

    // 2) chunked selective scan with fused depthwise conv + SiLU + gating
    scan_stats_fused<<<(BATCH * NCHUNK * INNER) / 256, 256, 0, stream>>>(
        xr, conv_w, conv_b, A_log, Hc, Dsum);
    scan_carry<<<(BATCH * STATE_DIM * INNER) / 256, 256, 0, stream>>>(
        Hc, Dsum, A_log);
    scan_apply_fused<<<(BATCH * NCHUNK * INNER) / 256, 256, 0, stream>>>(
        xr, conv_w, conv_b, A_log, Dv, Hc, y_bf);

    // 3) out = y @ W_out.T  (4096 x 1024, K=2048) -- bf16 MFMA
    gemm_bf16_nt<128,64,2,2><<<dim3(N2/64, M_TOT/128), 256, 0, stream>>>(
        y_bf, Wout_bf, out, M_TOT, N2, K2);
}

// Round 7
// 250.720 us; speedup vs baseline: 11.4850x; 1.0308x over previous
//
#include <hip/hip_runtime.h>
#include <hip/hip_bf16.h>
#include <math.h>

// Problem constants (from reference)
#define INPUT_DIM 1024
#define STATE_DIM 16
#define CONV_KK   4
#define INNER     2048          // INPUT_DIM * EXPAND
#define BATCH     2
#define SEQ       2048
#define M_TOT     (BATCH*SEQ)   // 4096
#define N1        (2*INNER)     // 4096
#define K1        INPUT_DIM     // 1024
#define N2        INPUT_DIM     // 1024
#define K2        INNER         // 2048
#define NCHUNK    64
#define CLEN      (SEQ/NCHUNK)  // 32

typedef __attribute__((ext_vector_type(8))) short short8;
typedef __attribute__((ext_vector_type(4))) float f32x4;
typedef unsigned short ushort;

// ---- fast transcendentals (threshold is 1.16e-2; these are ~1e-6 rel) ----
__device__ __forceinline__ float fast_softplus(float x) {
    return x > 20.f ? x : __logf(1.f + __expf(x));
}
__device__ __forceinline__ float fast_silu(float x) {
    return x * __builtin_amdgcn_rcpf(1.f + __expf(-x));
}
__device__ __forceinline__ ushort f2bf(float f) {
    unsigned u = __float_as_uint(f);
    u = (u + 0x7FFF + ((u >> 16) & 1)) >> 16;   // RNE
    return (ushort)u;
}

// ---------------------------------------------------------------------------
// Fused f32 -> bf16 convert for x, W_in, W_out (one kernel, 3 ranges).
// 8 floats / thread.
// ---------------------------------------------------------------------------
__global__ __launch_bounds__(256) void cvt_bf16_fused(
        const float* __restrict__ x,   ushort* __restrict__ x_bf,
        const float* __restrict__ wi,  ushort* __restrict__ wi_bf,
        const float* __restrict__ wo,  ushort* __restrict__ wo_bf)
{
    const int NA = M_TOT * K1 / 8;        // 524288
    const int NB = N1 * K1 / 8;           // 524288
    int i = blockIdx.x * 256 + threadIdx.x;
    const float* in; ushort* out; int idx;
    if (i < NA)            { in = x;  out = x_bf;  idx = i; }
    else if (i < NA + NB)  { in = wi; out = wi_bf; idx = i - NA; }
    else                   { in = wo; out = wo_bf; idx = i - NA - NB; }
    const float4* p = (const float4*)in + (size_t)idx * 2;
    float4 v0 = p[0], v1 = p[1];
    ushort u[8] = { f2bf(v0.x), f2bf(v0.y), f2bf(v0.z), f2bf(v0.w),
                    f2bf(v1.x), f2bf(v1.y), f2bf(v1.z), f2bf(v1.w) };
    *(short8*)(out + (size_t)idx * 8) = *(short8*)u;
}

// ---------------------------------------------------------------------------
// bf16 MFMA GEMM, NT form: C[m][n] = sum_k A[m*K+k]*B[n*K+k], C in f32.
// BK=64 (half the barrier drains of BK=32) + conflict-free XOR swizzle:
//   physical 16B-slot within a 128B LDS row = logical_slot ^ (row & 7).
// Rule #21 both-sides: global_load_lds dest stays LINEAR; the SOURCE global
// address is pre-swizzled (lane reads col-slot (lane&7)^(lane>>3)), and the
// ds_read applies the same XOR. Bank check: 64 lanes -> exactly 2/bank (free).
// ---------------------------------------------------------------------------
template<int BM, int BN, int WROWS, int WCOLS>
__global__ __launch_bounds__(256) void gemm_bf16_nt(
        const ushort* __restrict__ A, const ushort* __restrict__ B,
        float* __restrict__ C, int M, int N, int K)
{
    constexpr int MR = BM / WROWS / 16;
    constexpr int NR = BN / WCOLS / 16;
    __shared__ ushort As[BM][64];
    __shared__ ushort Bs[BN][64];

    const int tid  = threadIdx.x;
    const int w    = tid >> 6;
    const int lane = tid & 63;
    const int bm   = blockIdx.y * BM;
    const int bn   = blockIdx.x * BN;
    const int wm0  = (w / WCOLS) * (BM / WROWS);
    const int wn0  = (w % WCOLS) * (BN / WCOLS);

    // staging geometry: one global_load_lds = 64 lanes x 16B = 8 rows x 128B
    const int srow  = lane >> 3;                       // row within 8-row chunk
    const int sslot = (lane & 7) ^ srow;               // pre-swizzled src slot
    const int scol  = sslot * 8;                       // element offset (16B slot)

    f32x4 acc[MR][NR] = {};

    for (int k0 = 0; k0 < K; k0 += 64) {
        __syncthreads();
#pragma unroll
        for (int j8 = w; j8 < BM / 8; j8 += 4) {
            const ushort* ga = A + (size_t)(bm + j8 * 8 + srow) * K + k0 + scol;
            __builtin_amdgcn_global_load_lds(
                (const __attribute__((address_space(1))) void*)ga,
                (__attribute__((address_space(3))) void*)&As[j8 * 8][0], 16, 0, 0);
        }
#pragma unroll
        for (int j8 = w; j8 < BN / 8; j8 += 4) {
            const ushort* gb = B + (size_t)(bn + j8 * 8 + srow) * K + k0 + scol;
            __builtin_amdgcn_global_load_lds(
                (const __attribute__((address_space(1))) void*)gb,
                (__attribute__((address_space(3))) void*)&Bs[j8 * 8][0], 16, 0, 0);
        }
        __syncthreads();

        // fragment reads: row&7 == lane&7 (wm0/wn0, i*16 are multiples of 8)
#pragma unroll
        for (int ks = 0; ks < 2; ks++) {
            const int lslot = ks * 4 + (lane >> 4);        // logical 16B slot
            const int pcol  = (lslot ^ (lane & 7)) * 8;    // swizzled element col
            short8 a[MR], b[NR];
#pragma unroll
            for (int i = 0; i < MR; i++)
                a[i] = *(const short8*)&As[wm0 + i * 16 + (lane & 15)][pcol];
#pragma unroll
            for (int j = 0; j < NR; j++)
                b[j] = *(const short8*)&Bs[wn0 + j * 16 + (lane & 15)][pcol];
#pragma unroll
            for (int i = 0; i < MR; i++)
#pragma unroll
                for (int j = 0; j < NR; j++)
                    acc[i][j] = __builtin_amdgcn_mfma_f32_16x16x32_bf16(
                        a[i], b[j], acc[i][j], 0, 0, 0);
        }
    }

    // epilogue: D row=(lane>>4)*4+r, col=lane&15  [verified m89/m91]
#pragma unroll
    for (int i = 0; i < MR; i++)
#pragma unroll
        for (int j = 0; j < NR; j++)
#pragma unroll
            for (int r = 0; r < 4; r++) {
                int row = bm + wm0 + i * 16 + (lane >> 4) * 4 + r;
                int col = bn + wn0 + j * 16 + (lane & 15);
                C[(size_t)row * N + col] = acc[i][j][r];
            }
}

// ---------------------------------------------------------------------------
// Scan pass A (fused conv+SiLU): one thread per (b,chunk,c), 16 states in
// registers. Emits per-chunk end state (h0=0) and sum(delta).
// Hc layout: [B][NCHUNK][16][INNER] ; Dsum: [B][NCHUNK][INNER]
// ---------------------------------------------------------------------------
__global__ __launch_bounds__(256) void scan_stats_fused(
        const float* __restrict__ xr,       // (B*S, 4096)
        const float* __restrict__ conv_w,   // (INNER,1,4)
        const float* __restrict__ conv_b,   // (INNER)
        const float* __restrict__ A_log,    // (INNER,16)
        float* __restrict__ Hc,
        float* __restrict__ Dsum)
{
    const int gid = blockIdx.x * 256 + threadIdx.x;   // (b, chunk, c), c fastest
    const int c     = gid & (INNER - 1);
    const int chunk = (gid >> 11) & (NCHUNK - 1);
    const int b     = gid >> 17;

    const float4 w4  = *(const float4*)(conv_w + c * 4);
    const float bias = conv_b[c];

    float negA[16];
    {
        const float4* ap = (const float4*)(A_log + c * 16);
#pragma unroll
        for (int q = 0; q < 4; q++) {
            float4 v = ap[q];
            negA[q*4+0] = -__expf(v.x); negA[q*4+1] = -__expf(v.y);
            negA[q*4+2] = -__expf(v.z); negA[q*4+3] = -__expf(v.w);
        }
    }

    const int s0 = chunk * CLEN;
    const float* xp = xr + ((size_t)(b * SEQ + s0)) * N1 + c;

    float xm1 = 0.f, xm2 = 0.f, xm3 = 0.f;
    if (s0 > 0) { xm1 = xp[-N1]; xm2 = xp[-2*N1]; xm3 = xp[-3*N1]; }

    float h[16] = {};
    float dsum = 0.f;
    for (int s = 0; s < CLEN; s++) {
        float x0  = xp[(size_t)s * N1];
        float acc = bias + w4.x*xm3 + w4.y*xm2 + w4.z*xm1 + w4.w*x0;
        xm3 = xm2; xm2 = xm1; xm1 = x0;
        float xc    = fast_silu(acc);
        float delta = fast_softplus(xc);
        dsum += delta;
        float bx = xc * xc;
#pragma unroll
        for (int st = 0; st < 16; st++)
            h[st] = __expf(delta * negA[st]) * h[st] + bx;
    }

    const size_t cb = (size_t)b * NCHUNK + chunk;
#pragma unroll
    for (int st = 0; st < 16; st++)
        Hc[(cb * 16 + st) * INNER + c] = h[st];
    Dsum[cb * INNER + c] = dsum;
}

// ---------------------------------------------------------------------------
// Pass B: carry propagation across NCHUNK chunks; Hc becomes init states.
// ---------------------------------------------------------------------------
__global__ __launch_bounds__(256) void scan_carry(
        float* __restrict__ Hc,
        const float* __restrict__ Dsum,
        const float* __restrict__ A_log)
{
    const int tid = blockIdx.x * 256 + threadIdx.x;
    const int c  = tid & (INNER - 1);
    const int st = (tid >> 11) & 15;
    const int b  = tid >> 15;

    const float negA = -__expf(A_log[c * STATE_DIM + st]);
    float carry = 0.f;
    for (int j = 0; j < NCHUNK; j++) {
        const size_t cb  = (size_t)b * NCHUNK + j;
        const size_t idx = (cb * 16 + st) * INNER + c;
        float hend = Hc[idx];
        float P    = __expf(Dsum[cb * INNER + c] * negA);
        Hc[idx] = carry;
        carry = P * carry + hend;
    }
}

// ---------------------------------------------------------------------------
// Pass C (fused conv+SiLU + scan + gating): recompute chunk from init state,
// emit y as bf16.
// ---------------------------------------------------------------------------
__global__ __launch_bounds__(256) void scan_apply_fused(
        const float* __restrict__ xr,
        const float* __restrict__ conv_w,
        const float* __restrict__ conv_b,
        const float* __restrict__ A_log,
        const float* __restrict__ Dv,
        const float* __restrict__ Hc,       // init states
        ushort* __restrict__ y_bf)          // (B*S, INNER) bf16
{
    const int gid = blockIdx.x * 256 + threadIdx.x;
    const int c     = gid & (INNER - 1);
    const int chunk = (gid >> 11) & (NCHUNK - 1);
    const int b     = gid >> 17;

    const float4 w4  = *(const float4*)(conv_w + c * 4);
    const float bias = conv_b[c];
    const float Dc   = Dv[c];

    float negA[16];
    {
        const float4* ap = (const float4*)(A_log + c * 16);
#pragma unroll
        for (int q = 0; q < 4; q++) {
            float4 v = ap[q];
            negA[q*4+0] = -__expf(v.x); negA[q*4+1] = -__expf(v.y);
            negA[q*4+2] = -__expf(v.z); negA[q*4+3] = -__expf(v.w);
        }
    }

    const int s0 = chunk * CLEN;
    const size_t row0 = (size_t)(b * SEQ + s0);
    const float* xp = xr + row0 * N1 + c;
    const float* rp = xr + row0 * N1 + INNER + c;
    ushort*      yp = y_bf + row0 * INNER + c;

    float xm1 = 0.f, xm2 = 0.f, xm3 = 0.f;
    if (s0 > 0) { xm1 = xp[-N1]; xm2 = xp[-2*N1]; xm3 = xp[-3*N1]; }

    const size_t cb = (size_t)b * NCHUNK + chunk;
    float h[16];
#pragma unroll
    for (int st = 0; st < 16; st++)
        h[st] = Hc[(cb * 16 + st) * INNER + c];

    for (int s = 0; s < CLEN; s++) {
        float x0  = xp[(size_t)s * N1];
        float acc = bias + w4.x*xm3 + w4.y*xm2 + w4.z*xm1 + w4.w*x0;
        xm3 = xm2; xm2 = xm1; xm1 = x0;
        float xc    = fast_silu(acc);
        float delta = fast_softplus(xc);
        float bx    = xc * xc;
#pragma unroll
        for (int st = 0; st < 16; st++)
            h[st] = __expf(delta * negA[st]) * h[st] + bx;

        float s01 = (h[0]+h[1]) + (h[2]+h[3]);
        float s23 = (h[4]+h[5]) + (h[6]+h[7]);
        float s45 = (h[8]+h[9]) + (h[10]+h[11]);
        float s67 = (h[12]+h[13]) + (h[14]+h[15]);
        float sum = (s01 + s23) + (s45 + s67);

        float r = rp[(size_t)s * N1];
        float y = xc * sum * fast_silu(r) + Dc * xc;
        yp[(size_t)s * INNER] = f2bf(y);
    }
}

// ---------------------------------------------------------------------------
extern "C" void kernel_launch(void* const* d_in, const int* in_sizes, int n_in,
                              void* d_out, int out_size, void* d_ws, size_t ws_size,
                              hipStream_t stream)
{
    const float* x      = (const float*)d_in[0];
    const float* W_in   = (const float*)d_in[1];
    const float* conv_w = (const float*)d_in[2];
    const float* conv_b = (const float*)d_in[3];
    const float* A_log  = (const float*)d_in[4];
    const float* Dv     = (const float*)d_in[5];
    const float* W_out  = (const float*)d_in[6];
    float* out = (float*)d_out;

    // workspace layout (bytes)
    char* ws = (char*)d_ws;
    float*  xr      = (float*)ws;   ws += (size_t)M_TOT * N1 * 4;
    float*  Hc      = (float*)ws;   ws += (size_t)BATCH * NCHUNK * STATE_DIM * INNER * 4;
    float*  Dsum    = (float*)ws;   ws += (size_t)BATCH * NCHUNK * INNER * 4;
    ushort* x_bf    = (ushort*)ws;  ws += (size_t)M_TOT * K1 * 2;
    ushort* Win_bf  = (ushort*)ws;  ws += (size_t)N1 * K1 * 2;
    ushort* Wout_bf = (ushort*)ws;  ws += (size_t)N2 * K2 * 2;
    ushort* y_bf    = (ushort*)ws;  ws += (size_t)M_TOT * INNER * 2;

    // 0) fused f32 -> bf16 converts (x, W_in, W_out)
    {
        const int total8 = (M_TOT * K1 + N1 * K1 + N2 * K2) / 8;   // 1310720
        cvt_bf16_fused<<<total8 / 256, 256, 0, stream>>>(
            x, x_bf, W_in, Win_bf, W_out, Wout_bf);
    }

    // 1) xr = x @ W_in.T   (4096 x 4096, K=1024) -- bf16 MFMA, BK=64+swizzle
    gemm_bf16_nt<128,128,2,2><<<dim3(N1/128, M_TOT/128), 256, 0, stream>>>(
        x_bf, Win_bf, xr, M_TOT, N1, K1);

    // 2) chunked selective scan with fused depthwise conv + SiLU + gating
    scan_stats_fused<<<(BATCH * NCHUNK * INNER) / 256, 256, 0, stream>>>(
        xr, conv_w, conv_b, A_log, Hc, Dsum);
    scan_carry<<<(BATCH * STATE_DIM * INNER) / 256, 256, 0, stream>>>(
        Hc, Dsum, A_log);
    scan_apply_fused<<<(BATCH * NCHUNK * INNER) / 256, 256, 0, stream>>>(
        xr, conv_w, conv_b, A_log, Dv, Hc, y_bf);

    // 3) out = y @ W_out.T  (4096 x 1024, K=2048) -- bf16 MFMA, BK=64+swizzle
    gemm_bf16_nt<128,64,2,2><<<dim3(N2/64, M_TOT/128), 256, 0, stream>>>(
        y_bf, Wout_bf, out, M_TOT, N2, K2);
}

// Round 10
// 232.624 us; speedup vs baseline: 12.3784x; 1.0778x over previous
//
#include <hip/hip_runtime.h>
#include <hip/hip_bf16.h>
#include <math.h>

// Problem constants (from reference)
#define INPUT_DIM 1024
#define STATE_DIM 16
#define CONV_KK   4
#define INNER     2048          // INPUT_DIM * EXPAND
#define BATCH     2
#define SEQ       2048
#define M_TOT     (BATCH*SEQ)   // 4096
#define N1        (2*INNER)     // 4096
#define K1        INPUT_DIM     // 1024
#define N2        INPUT_DIM     // 1024
#define K2        INNER         // 2048
#define NCHUNK    64
#define CLEN      (SEQ/NCHUNK)  // 32

typedef __attribute__((ext_vector_type(8))) short short8;
typedef __attribute__((ext_vector_type(4))) float f32x4;
typedef unsigned short ushort;

#define LOG2E 1.44269504088896340736f

// ---- fast transcendentals (threshold is 1.16e-2; these are ~1e-6 rel) ----
__device__ __forceinline__ float fast_softplus(float x) {
    return x > 20.f ? x : __logf(1.f + __expf(x));
}
__device__ __forceinline__ float fast_silu(float x) {
    return x * __builtin_amdgcn_rcpf(1.f + __expf(-x));
}
__device__ __forceinline__ float exp2_fast(float t) {
#if __has_builtin(__builtin_amdgcn_exp2f)
    return __builtin_amdgcn_exp2f(t);      // v_exp_f32 (native exp2)
#else
    return __expf(t * 0.69314718055994531f);
#endif
}
__device__ __forceinline__ ushort f2bf(float f) {
    unsigned u = __float_as_uint(f);
    u = (u + 0x7FFF + ((u >> 16) & 1)) >> 16;   // RNE
    return (ushort)u;
}

// ---------------------------------------------------------------------------
// Fused f32 -> bf16 convert for x, W_in, W_out (one kernel, 3 ranges).
// ---------------------------------------------------------------------------
__global__ __launch_bounds__(256) void cvt_bf16_fused(
        const float* __restrict__ x,   ushort* __restrict__ x_bf,
        const float* __restrict__ wi,  ushort* __restrict__ wi_bf,
        const float* __restrict__ wo,  ushort* __restrict__ wo_bf)
{
    const int NA = M_TOT * K1 / 8;        // 524288
    const int NB = N1 * K1 / 8;           // 524288
    int i = blockIdx.x * 256 + threadIdx.x;
    const float* in; ushort* out; int idx;
    if (i < NA)            { in = x;  out = x_bf;  idx = i; }
    else if (i < NA + NB)  { in = wi; out = wi_bf; idx = i - NA; }
    else                   { in = wo; out = wo_bf; idx = i - NA - NB; }
    const float4* p = (const float4*)in + (size_t)idx * 2;
    float4 v0 = p[0], v1 = p[1];
    ushort u[8] = { f2bf(v0.x), f2bf(v0.y), f2bf(v0.z), f2bf(v0.w),
                    f2bf(v1.x), f2bf(v1.y), f2bf(v1.z), f2bf(v1.w) };
    *(short8*)(out + (size_t)idx * 8) = *(short8*)u;
}

// ---------------------------------------------------------------------------
// bf16 MFMA GEMM, NT form: C[m][n] = sum_k A[m*K+k]*B[n*K+k], C in f32.
// BK=64 + conflict-free both-sides XOR swizzle (verified r7: conflicts = 0).
// ---------------------------------------------------------------------------
template<int BM, int BN, int WROWS, int WCOLS>
__global__ __launch_bounds__(256) void gemm_bf16_nt(
        const ushort* __restrict__ A, const ushort* __restrict__ B,
        float* __restrict__ C, int M, int N, int K)
{
    constexpr int MR = BM / WROWS / 16;
    constexpr int NR = BN / WCOLS / 16;
    __shared__ ushort As[BM][64];
    __shared__ ushort Bs[BN][64];

    const int tid  = threadIdx.x;
    const int w    = tid >> 6;
    const int lane = tid & 63;
    const int bm   = blockIdx.y * BM;
    const int bn   = blockIdx.x * BN;
    const int wm0  = (w / WCOLS) * (BM / WROWS);
    const int wn0  = (w % WCOLS) * (BN / WCOLS);

    const int srow  = lane >> 3;                       // row within 8-row chunk
    const int sslot = (lane & 7) ^ srow;               // pre-swizzled src slot
    const int scol  = sslot * 8;

    f32x4 acc[MR][NR] = {};

    for (int k0 = 0; k0 < K; k0 += 64) {
        __syncthreads();
#pragma unroll
        for (int j8 = w; j8 < BM / 8; j8 += 4) {
            const ushort* ga = A + (size_t)(bm + j8 * 8 + srow) * K + k0 + scol;
            __builtin_amdgcn_global_load_lds(
                (const __attribute__((address_space(1))) void*)ga,
                (__attribute__((address_space(3))) void*)&As[j8 * 8][0], 16, 0, 0);
        }
#pragma unroll
        for (int j8 = w; j8 < BN / 8; j8 += 4) {
            const ushort* gb = B + (size_t)(bn + j8 * 8 + srow) * K + k0 + scol;
            __builtin_amdgcn_global_load_lds(
                (const __attribute__((address_space(1))) void*)gb,
                (__attribute__((address_space(3))) void*)&Bs[j8 * 8][0], 16, 0, 0);
        }
        __syncthreads();

#pragma unroll
        for (int ks = 0; ks < 2; ks++) {
            const int lslot = ks * 4 + (lane >> 4);
            const int pcol  = (lslot ^ (lane & 7)) * 8;
            short8 a[MR], b[NR];
#pragma unroll
            for (int i = 0; i < MR; i++)
                a[i] = *(const short8*)&As[wm0 + i * 16 + (lane & 15)][pcol];
#pragma unroll
            for (int j = 0; j < NR; j++)
                b[j] = *(const short8*)&Bs[wn0 + j * 16 + (lane & 15)][pcol];
#pragma unroll
            for (int i = 0; i < MR; i++)
#pragma unroll
                for (int j = 0; j < NR; j++)
                    acc[i][j] = __builtin_amdgcn_mfma_f32_16x16x32_bf16(
                        a[i], b[j], acc[i][j], 0, 0, 0);
        }
    }

    // epilogue: D row=(lane>>4)*4+r, col=lane&15  [verified m89/m91]
#pragma unroll
    for (int i = 0; i < MR; i++)
#pragma unroll
        for (int j = 0; j < NR; j++)
#pragma unroll
            for (int r = 0; r < 4; r++) {
                int row = bm + wm0 + i * 16 + (lane >> 4) * 4 + r;
                int col = bn + wn0 + j * 16 + (lane & 15);
                C[(size_t)row * N + col] = acc[i][j][r];
            }
}

// ---------------------------------------------------------------------------
// Scan pass A (fused conv+SiLU): one thread per (b,chunk,c), 16 states in
// registers; 4-step load batching; exp2 with pre-scaled negA2.
// Hc layout: [B][NCHUNK][16][INNER] ; Dsum: [B][NCHUNK][INNER]
// ---------------------------------------------------------------------------
__global__ __launch_bounds__(256) void scan_stats_fused(
        const float* __restrict__ xr,       // (B*S, 4096)
        const float* __restrict__ conv_w,   // (INNER,1,4)
        const float* __restrict__ conv_b,   // (INNER)
        const float* __restrict__ A_log,    // (INNER,16)
        float* __restrict__ Hc,
        float* __restrict__ Dsum)
{
    const int gid = blockIdx.x * 256 + threadIdx.x;   // (b, chunk, c), c fastest
    const int c     = gid & (INNER - 1);
    const int chunk = (gid >> 11) & (NCHUNK - 1);
    const int b     = gid >> 17;

    const float4 w4  = *(const float4*)(conv_w + c * 4);
    const float bias = conv_b[c];

    float negA2[16];   // -exp(A_log) * log2(e)
    {
        const float4* ap = (const float4*)(A_log + c * 16);
#pragma unroll
        for (int q = 0; q < 4; q++) {
            float4 v = ap[q];
            negA2[q*4+0] = -__expf(v.x) * LOG2E; negA2[q*4+1] = -__expf(v.y) * LOG2E;
            negA2[q*4+2] = -__expf(v.z) * LOG2E; negA2[q*4+3] = -__expf(v.w) * LOG2E;
        }
    }

    const int s0 = chunk * CLEN;
    const float* xp = xr + ((size_t)(b * SEQ + s0)) * N1 + c;

    float xm1 = 0.f, xm2 = 0.f, xm3 = 0.f;
    if (s0 > 0) { xm1 = xp[-N1]; xm2 = xp[-2*N1]; xm3 = xp[-3*N1]; }

    float h[16] = {};
    float dsum = 0.f;
    for (int s4 = 0; s4 < CLEN; s4 += 4) {
        float xv[4];
#pragma unroll
        for (int j = 0; j < 4; j++)
            xv[j] = xp[(size_t)(s4 + j) * N1];
#pragma unroll
        for (int j = 0; j < 4; j++) {
            float x0  = xv[j];
            float a4  = bias + w4.x*xm3 + w4.y*xm2 + w4.z*xm1 + w4.w*x0;
            xm3 = xm2; xm2 = xm1; xm1 = x0;
            float xc    = fast_silu(a4);
            float delta = fast_softplus(xc);
            dsum += delta;
            float bx = xc * xc;
#pragma unroll
            for (int st = 0; st < 16; st++)
                h[st] = exp2_fast(delta * negA2[st]) * h[st] + bx;
        }
    }

    const size_t cb = (size_t)b * NCHUNK + chunk;
#pragma unroll
    for (int st = 0; st < 16; st++)
        Hc[(cb * 16 + st) * INNER + c] = h[st];
    Dsum[cb * INNER + c] = dsum;
}

// ---------------------------------------------------------------------------
// Pass B: carry propagation across NCHUNK chunks; Hc becomes init states.
// unroll 4 -> loads batch ahead of the dependent exp/fma chain.
// ---------------------------------------------------------------------------
__global__ __launch_bounds__(256) void scan_carry(
        float* __restrict__ Hc,
        const float* __restrict__ Dsum,
        const float* __restrict__ A_log)
{
    const int tid = blockIdx.x * 256 + threadIdx.x;
    const int c  = tid & (INNER - 1);
    const int st = (tid >> 11) & 15;
    const int b  = tid >> 15;

    const float negA2 = -__expf(A_log[c * STATE_DIM + st]) * LOG2E;
    float carry = 0.f;
#pragma unroll 4
    for (int j = 0; j < NCHUNK; j++) {
        const size_t cb  = (size_t)b * NCHUNK + j;
        const size_t idx = (cb * 16 + st) * INNER + c;
        float hend = Hc[idx];
        float P    = exp2_fast(Dsum[cb * INNER + c] * negA2);
        Hc[idx] = carry;
        carry = P * carry + hend;
    }
}

// ---------------------------------------------------------------------------
// Pass C (fused conv+SiLU + scan + gating): recompute chunk from init state,
// emit y as bf16. 4-step load batching for x and res streams.
// ---------------------------------------------------------------------------
__global__ __launch_bounds__(256) void scan_apply_fused(
        const float* __restrict__ xr,
        const float* __restrict__ conv_w,
        const float* __restrict__ conv_b,
        const float* __restrict__ A_log,
        const float* __restrict__ Dv,
        const float* __restrict__ Hc,       // init states
        ushort* __restrict__ y_bf)          // (B*S, INNER) bf16
{
    const int gid = blockIdx.x * 256 + threadIdx.x;
    const int c     = gid & (INNER - 1);
    const int chunk = (gid >> 11) & (NCHUNK - 1);
    const int b     = gid >> 17;

    const float4 w4  = *(const float4*)(conv_w + c * 4);
    const float bias = conv_b[c];
    const float Dc   = Dv[c];

    float negA2[16];
    {
        const float4* ap = (const float4*)(A_log + c * 16);
#pragma unroll
        for (int q = 0; q < 4; q++) {
            float4 v = ap[q];
            negA2[q*4+0] = -__expf(v.x) * LOG2E; negA2[q*4+1] = -__expf(v.y) * LOG2E;
            negA2[q*4+2] = -__expf(v.z) * LOG2E; negA2[q*4+3] = -__expf(v.w) * LOG2E;
        }
    }

    const int s0 = chunk * CLEN;
    const size_t row0 = (size_t)(b * SEQ + s0);
    const float* xp = xr + row0 * N1 + c;
    const float* rp = xr + row0 * N1 + INNER + c;
    ushort*      yp = y_bf + row0 * INNER + c;

    float xm1 = 0.f, xm2 = 0.f, xm3 = 0.f;
    if (s0 > 0) { xm1 = xp[-N1]; xm2 = xp[-2*N1]; xm3 = xp[-3*N1]; }

    const size_t cb = (size_t)b * NCHUNK + chunk;
    float h[16];
#pragma unroll
    for (int st = 0; st < 16; st++)
        h[st] = Hc[(cb * 16 + st) * INNER + c];

    for (int s4 = 0; s4 < CLEN; s4 += 4) {
        float xv[4], rv[4];
#pragma unroll
        for (int j = 0; j < 4; j++) {
            xv[j] = xp[(size_t)(s4 + j) * N1];
            rv[j] = rp[(size_t)(s4 + j) * N1];
        }
#pragma unroll
        for (int j = 0; j < 4; j++) {
            float x0  = xv[j];
            float a4  = bias + w4.x*xm3 + w4.y*xm2 + w4.z*xm1 + w4.w*x0;
            xm3 = xm2; xm2 = xm1; xm1 = x0;
            float xc    = fast_silu(a4);
            float delta = fast_softplus(xc);
            float bx    = xc * xc;
#pragma unroll
            for (int st = 0; st < 16; st++)
                h[st] = exp2_fast(delta * negA2[st]) * h[st] + bx;

            float s01 = (h[0]+h[1]) + (h[2]+h[3]);
            float s23 = (h[4]+h[5]) + (h[6]+h[7]);
            float s45 = (h[8]+h[9]) + (h[10]+h[11]);
            float s67 = (h[12]+h[13]) + (h[14]+h[15]);
            float sum = (s01 + s23) + (s45 + s67);

            float r = rv[j];
            float y = xc * sum * fast_silu(r) + Dc * xc;
            yp[(size_t)(s4 + j) * INNER] = f2bf(y);
        }
    }
}

// ---------------------------------------------------------------------------
extern "C" void kernel_launch(void* const* d_in, const int* in_sizes, int n_in,
                              void* d_out, int out_size, void* d_ws, size_t ws_size,
                              hipStream_t stream)
{
    const float* x      = (const float*)d_in[0];
    const float* W_in   = (const float*)d_in[1];
    const float* conv_w = (const float*)d_in[2];
    const float* conv_b = (const float*)d_in[3];
    const float* A_log  = (const float*)d_in[4];
    const float* Dv     = (const float*)d_in[5];
    const float* W_out  = (const float*)d_in[6];
    float* out = (float*)d_out;

    // workspace layout (bytes)
    char* ws = (char*)d_ws;
    float*  xr      = (float*)ws;   ws += (size_t)M_TOT * N1 * 4;
    float*  Hc      = (float*)ws;   ws += (size_t)BATCH * NCHUNK * STATE_DIM * INNER * 4;
    float*  Dsum    = (float*)ws;   ws += (size_t)BATCH * NCHUNK * INNER * 4;
    ushort* x_bf    = (ushort*)ws;  ws += (size_t)M_TOT * K1 * 2;
    ushort* Win_bf  = (ushort*)ws;  ws += (size_t)N1 * K1 * 2;
    ushort* Wout_bf = (ushort*)ws;  ws += (size_t)N2 * K2 * 2;
    ushort* y_bf    = (ushort*)ws;  ws += (size_t)M_TOT * INNER * 2;

    // 0) fused f32 -> bf16 converts (x, W_in, W_out)
    {
        const int total8 = (M_TOT * K1 + N1 * K1 + N2 * K2) / 8;   // 1310720
        cvt_bf16_fused<<<total8 / 256, 256, 0, stream>>>(
            x, x_bf, W_in, Win_bf, W_out, Wout_bf);
    }

    // 1) xr = x @ W_in.T   (4096 x 4096, K=1024) -- bf16 MFMA, BK=64+swizzle
    gemm_bf16_nt<128,128,2,2><<<dim3(N1/128, M_TOT/128), 256, 0, stream>>>(
        x_bf, Win_bf, xr, M_TOT, N1, K1);

    // 2) chunked selective scan with fused depthwise conv + SiLU + gating
    scan_stats_fused<<<(BATCH * NCHUNK * INNER) / 256, 256, 0, stream>>>(
        xr, conv_w, conv_b, A_log, Hc, Dsum);
    scan_carry<<<(BATCH * STATE_DIM * INNER) / 256, 256, 0, stream>>>(
        Hc, Dsum, A_log);
    scan_apply_fused<<<(BATCH * NCHUNK * INNER) / 256, 256, 0, stream>>>(
        xr, conv_w, conv_b, A_log, Dv, Hc, y_bf);

    // 3) out = y @ W_out.T  (4096 x 1024, K=2048) -- bf16 MFMA, BK=64+swizzle
    gemm_bf16_nt<128,64,2,2><<<dim3(N2/64, M_TOT/128), 256, 0, stream>>>(
        y_bf, Wout_bf, out, M_TOT, N2, K2);
}